// Round 9
// baseline (224.851 us; speedup 1.0000x reference)
//
#include <hip/hip_runtime.h>
#include <math.h>

// Problem constants
#define T_  204
#define I_  5
#define H_  24
#define L_  10
#define O_  612
#define Bsz 8192

typedef _Float16 half8 __attribute__((ext_vector_type(8)));
typedef _Float16 half2t __attribute__((ext_vector_type(2)));
typedef float    float4t __attribute__((ext_vector_type(4)));

union U16B { float4t f4; half8 h8; float f[4]; _Float16 h[8]; half2t h2[4]; };

__device__ __forceinline__ float fast_rcp(float x){ return __builtin_amdgcn_rcpf(x); }
__device__ __forceinline__ float fast_ex2(float x){ return __builtin_amdgcn_exp2f(x); }
__device__ __forceinline__ half2t pk2(float a, float b){
    return __builtin_bit_cast(half2t, __builtin_amdgcn_cvt_pkrtz(a, b));
}

#define MFMA16(a,b,c) __builtin_amdgcn_mfma_f32_16x16x32_f16((a),(b),(c),0,0,0)

#define L2E  1.44269504f
#define L2E2 2.88539008f

__device__ __forceinline__ float sigm2(float x){ return fast_rcp(1.f + fast_ex2(x * -L2E)); }
__device__ __forceinline__ float tanh2(float x){ return 2.f * fast_rcp(1.f + fast_ex2(x * -L2E2)) - 1.f; }

// Barrier that waits only LDS (lgkmcnt) -- does NOT drain vmcnt, so global
// prefetches stay in flight across the per-step rendezvous (unlike
// __syncthreads, which the compiler lowers with a full vmcnt(0) drain).
#define STEP_BARRIER() asm volatile("s_waitcnt lgkmcnt(0)\n\ts_barrier" ::: "memory")

// 2 waves per block, 16 elems per block. Wave w owns gate tiles 3w..3w+2
// (3 units/lane -> 30 transcendentals/step, half of R8) and fc0 rows 5w..5w+4.
// 512 blocks x 2 waves = 1024 waves = 1 per SIMD device-wide.
__global__ __launch_bounds__(128)
void lstm_mfma(const float* __restrict__ x,
               const float* __restrict__ W_ih,
               const float* __restrict__ W_hh,
               const float* __restrict__ b_ih,
               const float* __restrict__ b_hh,
               const float* __restrict__ fc0_w,
               const float* __restrict__ fc0_b,
               const float* __restrict__ out_w,
               const float* __restrict__ out_b,
               float* __restrict__ out)
{
    // h staging, double-buffered: 2 x 16 elems x 40 halves (80B rows)
    __shared__ __align__(16) _Float16 hL[2*16*40];
    __shared__ __align__(16) _Float16 actL[16*24];

    const int tid  = threadIdx.x;
    const int w    = tid >> 6;       // wave 0/1
    const int lane = tid & 63;
    const int m = lane & 15;         // element col / A row-within-tile
    const int q = lane >> 4;         // quad
    const int elem = blockIdx.x * 16 + m;

    const float4t zf4 = {0.f, 0.f, 0.f, 0.f};

    // ---- gate A-fragments, unit-ownership permutation (validated R8) ----
    // wave w, tile T3 (global tile gT=3w+T3): packed row m = gate (m&3) of
    // unit 6*(m>>2)+gT. Lane's D regs r of tile T3 = gate r of unit 6q+3w+T3.
    half8 Ag[3];
    const int g0 = m & 3, ub = 6 * (m >> 2);
    #pragma unroll
    for (int T3 = 0; T3 < 3; ++T3) {
        const int gT = 3*w + T3;
        const int srow = g0 * H_ + ub + gT;
        float wv[8];
        if (q < 3) {
            const float4t* pw = (const float4t*)(W_hh + srow*H_ + 8*q);
            float4t wa = pw[0], wb = pw[1];
            #pragma unroll
            for (int i = 0; i < 4; ++i) { wv[i] = wa[i]; wv[4+i] = wb[i]; }
        } else {
            #pragma unroll
            for (int i = 0; i < 8; ++i) wv[i] = 0.f;
            #pragma unroll
            for (int i = 0; i < I_; ++i) wv[i] = W_ih[srow*I_ + i];
            wv[5] = b_ih[srow] + b_hh[srow];
        }
        U16B tw;
        #pragma unroll
        for (int i = 0; i < 8; ++i) tw.h[i] = (_Float16)wv[i];
        Ag[T3] = tw.h8;
    }

    // ---- LDS half-indices (buffer offset added per step) ----
    const int hwIdx = m*40 + 6*q + 3*w;   // scatter: 3x b16 (units 6q+3w+{0,1,2})
    const int hrIdx = m*40 + 8*q;         // gather: b128 (q<3), 16B aligned

    const float* xp = x + (size_t)elem * (T_*I_);

    // ---- fc0 inline-load setup: wave w rows l=5w+m (m<5), k=8q+i (q<3) ----
    const bool fval = (m < 5) && (q < 3);
    const float* fbase = fc0_w + (size_t)(5*w + (m < 5 ? m : 0)) * (T_*H_) + 8*q;
    float4t fA0 = zf4, fA1 = zf4;         // stage for step t (cols t*24+8q..)
    if (fval) {
        fA0 = *(const float4t*)(fbase + 0);
        fA1 = *(const float4t*)(fbase + 4);
    }

    // ---- x prefetch (distance 2): xA holds x(t+1) ----
    float xA0=0,xA1=0,xA2=0,xA3=0,xA4=0;
    U16B B;
    if (q == 3) {
        B.h2[0] = pk2(xp[0], xp[1]);
        B.h2[1] = pk2(xp[2], xp[3]);
        B.h2[2] = pk2(xp[4], 1.0f);
        B.h2[3] = pk2(0.f, 0.f);
        xA0 = xp[I_+0]; xA1 = xp[I_+1]; xA2 = xp[I_+2]; xA3 = xp[I_+3]; xA4 = xp[I_+4];
    } else {
        B.f4 = zf4;   // h_0 = 0
    }

    float c_[3] = {0.f, 0.f, 0.f};
    float4t accF = zf4;

    // ================= time loop =================
    #pragma unroll 2
    for (int t = 0; t < T_; ++t) {
        // prefetches: x(t+2) [dist 2, covers HBM], fc0 cols (t+1) [dist 1, L2]
        float xB0=0,xB1=0,xB2=0,xB3=0,xB4=0;
        if (q == 3) {
            const int tp2 = (t + 2 < T_) ? t + 2 : T_ - 1;
            const float* xq = xp + tp2*I_;
            xB0 = xq[0]; xB1 = xq[1]; xB2 = xq[2]; xB3 = xq[3]; xB4 = xq[4];
        }
        float4t fB0 = zf4, fB1 = zf4;
        {
            const int tp1 = (t + 1 < T_) ? t + 1 : T_ - 1;
            if (fval) {
                fB0 = *(const float4t*)(fbase + tp1*H_ + 0);
                fB1 = *(const float4t*)(fbase + tp1*H_ + 4);
            }
        }

        // 3 gate MFMAs
        float4t D0 = MFMA16(Ag[0], B.h8, zf4);
        float4t D1 = MFMA16(Ag[1], B.h8, zf4);
        float4t D2 = MFMA16(Ag[2], B.h8, zf4);

        // in-lane cell update for units 6q+3w+T3
        const int bofs = (t & 1) * 640;
        {
            float4t D[3] = {D0, D1, D2};
            #pragma unroll
            for (int T3 = 0; T3 < 3; ++T3) {
                const float si = sigm2(D[T3][0]);
                const float sf = sigm2(D[T3][1]);
                const float tg = tanh2(D[T3][2]);
                const float so = sigm2(D[T3][3]);
                c_[T3] = fmaf(sf, c_[T3], si * tg);
                const float hh = so * tanh2(c_[T3]);
                hL[bofs + hwIdx + T3] = (_Float16)hh;
            }
        }

        STEP_BARRIER();   // lgkm-only wait + rendezvous (global loads stay in flight)

        // rebuild B-frag: q<3 gather h_t; q3 packs x(t+1) (+bias one)
        if (q < 3) {
            B.f4 = *(const float4t*)(&hL[bofs + hrIdx]);
        } else {
            B.h2[0] = pk2(xA0, xA1);
            B.h2[1] = pk2(xA2, xA3);
            B.h2[2] = pk2(xA4, 1.0f);
            B.h2[3] = pk2(0.f, 0.f);
        }

        // fc0 accumulation with h_t (A zero for k>=24 and m>=5)
        U16B fF;
        fF.h2[0] = pk2(fA0[0], fA0[1]);
        fF.h2[1] = pk2(fA0[2], fA0[3]);
        fF.h2[2] = pk2(fA1[0], fA1[1]);
        fF.h2[3] = pk2(fA1[2], fA1[3]);
        accF = MFMA16(fF.h8, B.h8, accF);

        fA0 = fB0; fA1 = fB1;
        xA0 = xB0; xA1 = xB1; xA2 = xB2; xA3 = xB3; xA4 = xB4;
    }

    // ================= epilogue =================
    // wave w holds fc0 rows l=5w+rid (rid=4q+r<5). Zero-pad k=10..15 (wave0)
    // so the out-MFMA's zero A rows never multiply poison NaNs.
    #pragma unroll
    for (int r = 0; r < 4; ++r) {
        const int rid = 4*q + r;
        if (rid < 5) {
            const int l = 5*w + rid;
            const float v = accF[r] + fc0_b[l];
            actL[m*24 + l] = (_Float16)fmaxf(v, 0.f);
        } else if (w == 0 && rid >= 10) {
            actL[m*24 + rid] = (_Float16)0.f;
        }
    }
    __syncthreads();

    U16B Ba;
    if (q < 2) Ba.f4 = *(const float4t*)(&actL[m*24 + 8*q]);
    else       Ba.f4 = zf4;            // k>=16 unused (out_w A-frag zero there)

    // out = act @ out_w^T + out_b : 39 tiles interleaved across the 2 waves
    for (int Tt = w; Tt < 39; Tt += 2) {
        const int row = 16*Tt + m;
        float w0=0.f,w1=0.f,w2=0.f,w3=0.f,w4=0.f,w5=0.f,w6=0.f,w7=0.f;
        if (row < O_ && q < 2) {
            const float2* p2 = (const float2*)(out_w + row*L_);
            if (q == 0) {
                float2 a = p2[0], b = p2[1], cc = p2[2], dd = p2[3];
                w0=a.x; w1=a.y; w2=b.x; w3=b.y; w4=cc.x; w5=cc.y; w6=dd.x; w7=dd.y;
            } else {
                float2 a = p2[4];
                w0=a.x; w1=a.y;
            }
        }
        U16B Aw;
        Aw.h2[0] = pk2(w0,w1); Aw.h2[1] = pk2(w2,w3);
        Aw.h2[2] = pk2(w4,w5); Aw.h2[3] = pk2(w6,w7);

        float4t dd = MFMA16(Aw.h8, Ba.h8, zf4);

        const int ob = 16*Tt + 4*q;
        if (ob < O_) {
            const float4t bias = *(const float4t*)(out_b + ob);
            #pragma unroll
            for (int r = 0; r < 4; ++r) dd[r] += bias[r];
            *(float4t*)(out + (size_t)elem*O_ + ob) = dd;
        }
    }
}

extern "C" void kernel_launch(void* const* d_in, const int* in_sizes, int n_in,
                              void* d_out, int out_size, void* d_ws, size_t ws_size,
                              hipStream_t stream)
{
    const float* x     = (const float*)d_in[0];
    const float* W_ih  = (const float*)d_in[1];
    const float* W_hh  = (const float*)d_in[2];
    const float* b_ih  = (const float*)d_in[3];
    const float* b_hh  = (const float*)d_in[4];
    const float* fc0_w = (const float*)d_in[5];
    const float* fc0_b = (const float*)d_in[6];
    const float* out_w = (const float*)d_in[7];
    const float* out_b = (const float*)d_in[8];
    float* out = (float*)d_out;
    (void)d_ws; (void)ws_size;

    lstm_mfma<<<dim3(Bsz/16), dim3(128), 0, stream>>>(
        x, W_ih, W_hh, b_ih, b_hh, fc0_w, fc0_b, out_w, out_b, out);
}